// Round 5
// baseline (144.140 us; speedup 1.0000x reference)
//
#include <hip/hip_runtime.h>
#include <hip/hip_cooperative_groups.h>
#include <math.h>

namespace cg = cooperative_groups;

#define N 512
#define DIM 128
#define NORM_S 3.0f
#define TR 64            // tile rows staged in LDS per iteration
#define PADS 132         // padded row stride (floats): float4-aligned, uniform banks

// ws layout: sums[N] | cnts[N]
//
// Single cooperative kernel, one block per anchor i:
//   phase 0: stage x_i + labels; rn_i from x_i
//   phase 1: LDS-tiled coalesced sweep over raw x: per row j compute BOTH
//            dot(x_i,x_j) and ||x_j||^2 (4 threads/row x 32 dims);
//            D_ij = 18*max(0, 1 - dot*rn_i*rn_j); compact same/diff lists
//   phase 2: softplus(D_same - D_diff) over ns x nd; per-block partial
//   phase 3: grid.sync(); block 0 reduces 512 partials -> out
__global__ void __launch_bounds__(256) triplet_kernel(const float* __restrict__ x,
                                                      const int* __restrict__ labels,
                                                      float* __restrict__ sums,
                                                      float* __restrict__ cnts,
                                                      float* __restrict__ out) {
    __shared__ float xt[TR * PADS];   // 33792 B
    __shared__ float xi[DIM];
    __shared__ int   lab[N];
    __shared__ float sameD[N];
    __shared__ float diffD[N];
    __shared__ float partd[256];      // dot partials
    __shared__ float parts[256];      // sumsq partials
    __shared__ float red[256];
    __shared__ float red2[256];
    __shared__ float rni_sh;
    __shared__ int   nsame, ndiff;

    int i = blockIdx.x;
    int t = threadIdx.x;

    if (t < DIM) xi[t] = x[i * DIM + t];
    for (int j = t; j < N; j += 256) lab[j] = labels[j];
    if (t == 0) { nsame = 0; ndiff = 0; }
    __syncthreads();

    // rn_i = 1/||x_i||
    red[t] = (t < DIM) ? xi[t] * xi[t] : 0.0f;
    __syncthreads();
    #pragma unroll
    for (int s = 128; s > 0; s >>= 1) {
        if (t < s) red[t] += red[t + s];
        __syncthreads();
    }
    if (t == 0) rni_sh = rsqrtf(red[0]);
    __syncthreads();

    int li  = lab[i];
    float rni = rni_sh;
    int jloc  = t & (TR - 1);      // row within tile: 0..63
    int quart = t >> 6;            // 0..3
    int dbase = quart * 32;        // this thread's 32-dim slice

    // preload x_i slice into registers (tile-invariant)
    float4 bx[8];
    {
        const float4* b = (const float4*)(xi + dbase);
        #pragma unroll
        for (int q = 0; q < 8; ++q) bx[q] = b[q];
    }

    for (int tile = 0; tile < N / TR; ++tile) {
        int base = tile * TR;
        // stage tile of raw x: TR*DIM floats = 2048 float4, 8/thread, coalesced
        const float4* src = (const float4*)(x + base * DIM);
        #pragma unroll
        for (int k = 0; k < (TR * DIM / 4) / 256; ++k) {
            int e  = t + k * 256;
            int r  = e >> 5;       // 32 float4 per row
            int c4 = e & 31;
            float4 v = src[e];
            *((float4*)(xt + r * PADS + 4 * c4)) = v;
        }
        __syncthreads();

        // split-K: dot slice + sumsq slice for row jloc, dims [dbase, dbase+32)
        {
            const float4* a = (const float4*)(xt + jloc * PADS + dbase);
            float d0 = 0.0f, d1 = 0.0f, s0 = 0.0f, s1 = 0.0f;
            #pragma unroll
            for (int q = 0; q < 8; q += 2) {
                float4 a0 = a[q + 0];
                float4 a1 = a[q + 1];
                d0 += a0.x * bx[q].x + a0.y * bx[q].y + a0.z * bx[q].z + a0.w * bx[q].w;
                d1 += a1.x * bx[q + 1].x + a1.y * bx[q + 1].y + a1.z * bx[q + 1].z + a1.w * bx[q + 1].w;
                s0 += a0.x * a0.x + a0.y * a0.y + a0.z * a0.z + a0.w * a0.w;
                s1 += a1.x * a1.x + a1.y * a1.y + a1.z * a1.z + a1.w * a1.w;
            }
            partd[t] = d0 + d1;
            parts[t] = s0 + s1;
        }
        __syncthreads();

        if (t < TR) {
            float dot = partd[t] + partd[t + 64] + partd[t + 128] + partd[t + 192];
            float ss  = parts[t] + parts[t + 64] + parts[t + 128] + parts[t + 192];
            float rnj = rsqrtf(ss);
            int j = base + t;
            // D = max(0, 18 - 2*9*dot/(||xi|| ||xj||)) = 18*max(0, 1 - dot*rni*rnj)
            float D = 18.0f * fmaxf(0.0f, 1.0f - dot * rni * rnj);
            int lj = lab[j];
            if (lj == li) {
                if (j != i) { int p = atomicAdd(&nsame, 1); sameD[p] = D; }
            } else {
                int p = atomicAdd(&ndiff, 1); diffD[p] = D;
            }
        }
        __syncthreads();   // lists/partials settled before next tile overwrites
    }

    int ns = nsame, nd = ndiff;
    float lsum = 0.0f;
    for (int js = 0; js < ns; ++js) {
        float Dij = sameD[js];
        for (int ks = t; ks < nd; ks += 256) {
            // d in [-36,36]: expf can't overflow fp32; no stabilization needed.
            float d = Dij - diffD[ks];
            lsum += __logf(1.0f + __expf(d));
        }
    }

    red[t] = lsum;
    __syncthreads();
    #pragma unroll
    for (int s = 128; s > 0; s >>= 1) {
        if (t < s) red[t] += red[t + s];
        __syncthreads();
    }
    if (t == 0) {
        sums[i] = red[0];
        cnts[i] = (float)(ns * nd);
    }
    __threadfence();               // device-scope visibility across XCDs

    cg::this_grid().sync();

    if (i == 0) {
        float sv = sums[t] + sums[t + 256];
        float cv = cnts[t] + cnts[t + 256];
        red[t]  = sv;
        red2[t] = cv;
        __syncthreads();
        #pragma unroll
        for (int s = 128; s > 0; s >>= 1) {
            if (t < s) {
                red[t]  += red[t + s];
                red2[t] += red2[t + s];
            }
            __syncthreads();
        }
        if (t == 0) out[0] = red[0] / red2[0];
    }
}

extern "C" void kernel_launch(void* const* d_in, const int* in_sizes, int n_in,
                              void* d_out, int out_size, void* d_ws, size_t ws_size,
                              hipStream_t stream) {
    const float* x      = (const float*)d_in[0];
    const int*   labels = (const int*)d_in[1];
    float*       out    = (float*)d_out;

    float* sums = (float*)d_ws;   // 512 floats
    float* cnts = sums + N;       // 512 floats

    void* args[] = {(void*)&x, (void*)&labels, (void*)&sums, (void*)&cnts, (void*)&out};
    hipLaunchCooperativeKernel((const void*)triplet_kernel,
                               dim3(N), dim3(256), args, 0, stream);
}

// Round 6
// 72.917 us; speedup vs baseline: 1.9768x; 1.9768x over previous
//
#include <hip/hip_runtime.h>
#include <math.h>

#define N 512
#define DIM 128
#define NORM_S 3.0f
#define TR 64            // tile rows staged in LDS per iteration
#define PADS 132         // padded row stride (floats): float4-aligned, 2-way banks (free)

// ws layout: sums[N] | cnts[N]

// Fused kernel (regular launch, no grid sync): one block per anchor i.
//   phase 0: stage x_i + labels; rn_i = 1/||x_i||
//   phase 1: LDS-tiled coalesced sweep over raw x; per row j compute dot(x_i,x_j)
//            and ||x_j||^2 via 4 threads/row x 32 dims, reduced with __shfl_xor
//            (no LDS round-trip, no extra barrier); D = 18*max(0,1-dot*rni*rnj);
//            compact same/diff lists in LDS
//   phase 2: sum softplus(D_same - D_diff); one partial per block
__global__ void __launch_bounds__(256) triplet_kernel(const float* __restrict__ x,
                                                      const int* __restrict__ labels,
                                                      float* __restrict__ sums,
                                                      float* __restrict__ cnts) {
    __shared__ float xt[TR * PADS];   // 33792 B
    __shared__ float xi[DIM];
    __shared__ int   lab[N];
    __shared__ float sameD[N];
    __shared__ float diffD[N];
    __shared__ float red[256];
    __shared__ float rni_sh;
    __shared__ int   nsame, ndiff;

    int i = blockIdx.x;
    int t = threadIdx.x;

    if (t < DIM) xi[t] = x[i * DIM + t];
    for (int j = t; j < N; j += 256) lab[j] = labels[j];
    if (t == 0) { nsame = 0; ndiff = 0; }
    __syncthreads();

    // rn_i = 1/||x_i||  (one block reduction, happens once)
    red[t] = (t < DIM) ? xi[t] * xi[t] : 0.0f;
    __syncthreads();
    #pragma unroll
    for (int s = 128; s > 0; s >>= 1) {
        if (t < s) red[t] += red[t + s];
        __syncthreads();
    }
    if (t == 0) rni_sh = rsqrtf(red[0]);
    __syncthreads();

    int li  = lab[i];
    float rni = rni_sh;
    int quart = t & 3;             // 4 adjacent lanes per row -> shfl_xor 1,2
    int jloc  = t >> 2;            // row within tile: 0..63
    int dbase = quart * 32;        // this thread's 32-dim slice

    // preload x_i slice into registers (tile-invariant)
    float4 bx[8];
    {
        const float4* b = (const float4*)(xi + dbase);
        #pragma unroll
        for (int q = 0; q < 8; ++q) bx[q] = b[q];
    }

    for (int tile = 0; tile < N / TR; ++tile) {
        int base = tile * TR;
        // stage tile of raw x: TR*DIM floats = 2048 float4, 8/thread, coalesced
        const float4* src = (const float4*)(x + base * DIM);
        #pragma unroll
        for (int k = 0; k < (TR * DIM / 4) / 256; ++k) {
            int e  = t + k * 256;
            int r  = e >> 5;       // 32 float4 per row
            int c4 = e & 31;
            float4 v = src[e];
            *((float4*)(xt + r * PADS + 4 * c4)) = v;
        }
        __syncthreads();

        // split-K dot + sumsq for row jloc, dims [dbase, dbase+32)
        float dsum, ssum;
        {
            const float4* a = (const float4*)(xt + jloc * PADS + dbase);
            float d0 = 0.0f, d1 = 0.0f, s0 = 0.0f, s1 = 0.0f;
            #pragma unroll
            for (int q = 0; q < 8; q += 2) {
                float4 a0 = a[q + 0];
                float4 a1 = a[q + 1];
                d0 += a0.x * bx[q].x + a0.y * bx[q].y + a0.z * bx[q].z + a0.w * bx[q].w;
                d1 += a1.x * bx[q + 1].x + a1.y * bx[q + 1].y + a1.z * bx[q + 1].z + a1.w * bx[q + 1].w;
                s0 += a0.x * a0.x + a0.y * a0.y + a0.z * a0.z + a0.w * a0.w;
                s1 += a1.x * a1.x + a1.y * a1.y + a1.z * a1.z + a1.w * a1.w;
            }
            dsum = d0 + d1;
            ssum = s0 + s1;
        }
        // reduce across the 4 lanes of this row (no barrier, no LDS)
        dsum += __shfl_xor(dsum, 1, 64);
        dsum += __shfl_xor(dsum, 2, 64);
        ssum += __shfl_xor(ssum, 1, 64);
        ssum += __shfl_xor(ssum, 2, 64);

        if (quart == 0) {
            float rnj = rsqrtf(ssum);
            int j = base + jloc;
            // D = max(0, 18 - 2*9*dot/(||xi|| ||xj||)) = 18*max(0, 1 - dot*rni*rnj)
            float D = 18.0f * fmaxf(0.0f, 1.0f - dsum * rni * rnj);
            int lj = lab[j];
            if (lj == li) {
                if (j != i) { int p = atomicAdd(&nsame, 1); sameD[p] = D; }
            } else {
                int p = atomicAdd(&ndiff, 1); diffD[p] = D;
            }
        }
        __syncthreads();   // xt reads done before next tile overwrites
    }

    int ns = nsame, nd = ndiff;
    float lsum = 0.0f;
    for (int js = 0; js < ns; ++js) {
        float Dij = sameD[js];
        for (int ks = t; ks < nd; ks += 256) {
            // d in [-36,36]: expf can't overflow fp32; no stabilization needed.
            float d = Dij - diffD[ks];
            lsum += __logf(1.0f + __expf(d));
        }
    }

    red[t] = lsum;
    __syncthreads();
    #pragma unroll
    for (int s = 128; s > 0; s >>= 1) {
        if (t < s) red[t] += red[t + s];
        __syncthreads();
    }
    if (t == 0) {
        sums[i] = red[0];
        cnts[i] = (float)(ns * nd);
    }
}

// Reduce the 512 per-block partials (contention-free, separate dispatch —
// cheaper than cg grid.sync on this chip by ~50 us, see R5 post-mortem).
__global__ void __launch_bounds__(256) finalize_kernel(const float* __restrict__ sums,
                                                       const float* __restrict__ cnts,
                                                       float* __restrict__ out) {
    __shared__ float2 red[256];
    int t = threadIdx.x;
    float2 v;
    v.x = sums[t] + sums[t + 256];
    v.y = cnts[t] + cnts[t + 256];
    red[t] = v;
    __syncthreads();
    #pragma unroll
    for (int s = 128; s > 0; s >>= 1) {
        if (t < s) {
            red[t].x += red[t + s].x;
            red[t].y += red[t + s].y;
        }
        __syncthreads();
    }
    if (t == 0) out[0] = red[0].x / red[0].y;
}

extern "C" void kernel_launch(void* const* d_in, const int* in_sizes, int n_in,
                              void* d_out, int out_size, void* d_ws, size_t ws_size,
                              hipStream_t stream) {
    const float* x      = (const float*)d_in[0];
    const int*   labels = (const int*)d_in[1];
    float*       out    = (float*)d_out;

    float* sums = (float*)d_ws;   // 512 floats
    float* cnts = sums + N;       // 512 floats

    triplet_kernel<<<N, 256, 0, stream>>>(x, labels, sums, cnts);
    finalize_kernel<<<1, 256, 0, stream>>>(sums, cnts, out);
}

// Round 7
// 71.115 us; speedup vs baseline: 2.0269x; 1.0253x over previous
//
#include <hip/hip_runtime.h>
#include <math.h>

#define N 512
#define DIM 128
#define TR 128           // tile rows staged in LDS per iteration (4 tiles)
#define PADS 132         // padded row stride (floats): float4-aligned
#define BT 512           // threads per block: 2 blocks/CU -> 4 waves/SIMD

// ws layout: sums[N] | cnts[N]

// One block (512 thr) per anchor i.
//   phase 1: 4 LDS tiles of raw x (coalesced float4 staging); per row j:
//            dot(x_i,x_j) and ||x_j||^2 via 4 threads/row x 32 dims +
//            __shfl_xor; store dotv[j], ssqv[j]
//   phase 2: bulk D_j = 18*max(0, 1 - dotv*rni*rnj); compact same/diff lists
//   phase 3: thread-per-k softplus: ek=exp(-D_k) in register, ~15 serial js
//            iters of log(1 + exp(D_s)*ek); wave+LDS reduce; one partial/block
__global__ void __launch_bounds__(BT) triplet_kernel(const float* __restrict__ x,
                                                     const int* __restrict__ labels,
                                                     float* __restrict__ sums,
                                                     float* __restrict__ cnts) {
    __shared__ float xt[TR * PADS];   // 67584 B
    __shared__ int   lab[N];
    __shared__ float dotv[N];
    __shared__ float ssqv[N];
    __shared__ float sameD[N];
    __shared__ float diffD[N];
    __shared__ float red[BT / 64];
    __shared__ int   nsame, ndiff;

    int i = blockIdx.x;
    int t = threadIdx.x;

    lab[t] = labels[t];               // BT == N
    if (t == 0) { nsame = 0; ndiff = 0; }

    int quart = t & 3;                // 4 lanes per row -> shfl_xor 1,2
    int jloc  = t >> 2;               // row within tile: 0..127
    int dbase = quart * 32;           // this thread's 32-dim slice

    // anchor slice in registers (all waves read the same row: L1-broadcast)
    float4 bx[8];
    {
        const float4* b = (const float4*)(x + i * DIM + dbase);
        #pragma unroll
        for (int q = 0; q < 8; ++q) bx[q] = b[q];
    }
    __syncthreads();

    for (int tile = 0; tile < N / TR; ++tile) {
        int base = tile * TR;
        // stage tile: TR*DIM floats = 4096 float4, 8/thread, coalesced
        const float4* src = (const float4*)(x + base * DIM);
        #pragma unroll
        for (int k = 0; k < (TR * DIM / 4) / BT; ++k) {
            int e  = t + k * BT;
            int r  = e >> 5;          // 32 float4 per row
            int c4 = e & 31;
            float4 v = src[e];
            *((float4*)(xt + r * PADS + 4 * c4)) = v;
        }
        __syncthreads();

        // split-K dot + sumsq for row jloc, dims [dbase, dbase+32)
        const float4* a = (const float4*)(xt + jloc * PADS + dbase);
        float d0 = 0.0f, d1 = 0.0f, s0 = 0.0f, s1 = 0.0f;
        #pragma unroll
        for (int q = 0; q < 8; q += 2) {
            float4 a0 = a[q + 0];
            float4 a1 = a[q + 1];
            d0 += a0.x * bx[q].x + a0.y * bx[q].y + a0.z * bx[q].z + a0.w * bx[q].w;
            d1 += a1.x * bx[q + 1].x + a1.y * bx[q + 1].y + a1.z * bx[q + 1].z + a1.w * bx[q + 1].w;
            s0 += a0.x * a0.x + a0.y * a0.y + a0.z * a0.z + a0.w * a0.w;
            s1 += a1.x * a1.x + a1.y * a1.y + a1.z * a1.z + a1.w * a1.w;
        }
        float dsum = d0 + d1;
        float ssum = s0 + s1;
        dsum += __shfl_xor(dsum, 1, 64);
        dsum += __shfl_xor(dsum, 2, 64);
        ssum += __shfl_xor(ssum, 1, 64);
        ssum += __shfl_xor(ssum, 2, 64);
        if (quart == 0) {
            dotv[base + jloc] = dsum;
            ssqv[base + jloc] = ssum;
        }
        __syncthreads();   // xt reads done + partials visible before next tile
    }

    // bulk D + compaction (t == j; BT == N)
    {
        float rni = rsqrtf(ssqv[i]);
        int j = t;
        float D = 18.0f * fmaxf(0.0f, 1.0f - dotv[j] * rsqrtf(ssqv[j]) * rni);
        int li = lab[i];
        if (lab[j] == li) {
            if (j != i) { int p = atomicAdd(&nsame, 1); sameD[p] = D; }
        } else {
            int p = atomicAdd(&ndiff, 1); diffD[p] = D;
        }
    }
    __syncthreads();

    int ns = nsame, nd = ndiff;       // nd <= 511 < BT: one k per thread
    float ek = (t < nd) ? __expf(-diffD[t]) : 0.0f;   // t>=nd contributes log(1)=0
    float lsum = 0.0f;
    float snext = (ns > 0) ? sameD[0] : 0.0f;
    for (int js = 0; js < ns; ++js) {
        float ds = snext;
        snext = sameD[js + 1];        // js+1 <= ns <= 511: in-bounds; last read unused
        // softplus(ds - Dk) = log(1 + e^ds * e^-Dk); ds in [0,36]: no overflow in fp32
        float es = __expf(ds);
        lsum += __logf(1.0f + es * ek);
    }

    // wave-level reduce, then 8 wave partials through LDS
    #pragma unroll
    for (int off = 32; off > 0; off >>= 1) lsum += __shfl_xor(lsum, off, 64);
    if ((t & 63) == 0) red[t >> 6] = lsum;
    __syncthreads();
    if (t == 0) {
        float s = 0.0f;
        #pragma unroll
        for (int w = 0; w < BT / 64; ++w) s += red[w];
        sums[i] = s;
        cnts[i] = (float)(ns * nd);
    }
}

// Reduce the 512 per-block partials (contention-free; separate dispatch is
// ~50 us cheaper than cg grid.sync on this chip, see R5 post-mortem).
__global__ void __launch_bounds__(256) finalize_kernel(const float* __restrict__ sums,
                                                       const float* __restrict__ cnts,
                                                       float* __restrict__ out) {
    __shared__ float2 red[256];
    int t = threadIdx.x;
    float2 v;
    v.x = sums[t] + sums[t + 256];
    v.y = cnts[t] + cnts[t + 256];
    red[t] = v;
    __syncthreads();
    #pragma unroll
    for (int s = 128; s > 0; s >>= 1) {
        if (t < s) {
            red[t].x += red[t + s].x;
            red[t].y += red[t + s].y;
        }
        __syncthreads();
    }
    if (t == 0) out[0] = red[0].x / red[0].y;
}

extern "C" void kernel_launch(void* const* d_in, const int* in_sizes, int n_in,
                              void* d_out, int out_size, void* d_ws, size_t ws_size,
                              hipStream_t stream) {
    const float* x      = (const float*)d_in[0];
    const int*   labels = (const int*)d_in[1];
    float*       out    = (float*)d_out;

    float* sums = (float*)d_ws;   // 512 floats
    float* cnts = sums + N;       // 512 floats

    triplet_kernel<<<N, BT, 0, stream>>>(x, labels, sums, cnts);
    finalize_kernel<<<1, 256, 0, stream>>>(sums, cnts, out);
}